// Round 1
// baseline (7587.523 us; speedup 1.0000x reference)
//
#include <hip/hip_runtime.h>
#include <hip/hip_bf16.h>
#include <math.h>

// Problem constants
#define T 256
#define B 64
#define FEAT 256
#define HID 1024
#define NCLS 257
#define KTOT 1280            // HID + FEAT (z = [h, x_t])
#define NG 4096              // 4 gates * HID
#define KSPLIT 4
#define KCHUNK 320           // KTOT / KSPLIT
#define BK 32

// Hamilton block component/sign tables
__device__ __constant__ int   d_comp[4][4] = {{0,1,2,3},{1,0,3,2},{2,3,0,1},{3,2,1,0}};
__device__ __constant__ float d_sign[4][4] = {{ 1.f, 1.f, 1.f, 1.f},
                                              {-1.f, 1.f,-1.f, 1.f},
                                              {-1.f, 1.f, 1.f,-1.f},
                                              {-1.f,-1.f, 1.f, 1.f}};

// Build combined weight Wc [KTOT][NG]:
//   rows 0..1023   = Wh_full (Hamilton-expanded Wh), per-gate columns
//   rows 1024..1279 = Wx_full (Hamilton-expanded Wx)
// column n = g*HID + q*256 + bcol
__global__ __launch_bounds__(256) void build_wc(const float* __restrict__ Wh,
                                                const float* __restrict__ Wx,
                                                float* __restrict__ Wc) {
    int idx = blockIdx.x * 256 + threadIdx.x;
    if (idx >= KTOT * NG) return;
    int k = idx / NG, n = idx - (idx / NG) * NG;
    int g = n >> 10;
    int cn = n & 1023;
    int q = cn >> 8, bcol = cn & 255;
    float v;
    if (k < HID) {
        int p = k >> 8, a = k & 255;           // Wh: [4][4][256][256]
        int comp = d_comp[p][q];
        v = d_sign[p][q] * Wh[((g * 4 + comp) * 256 + a) * 256 + bcol];
    } else {
        int kk = k - HID;
        int p = kk >> 6, a = kk & 63;          // Wx: [4][4][64][256]
        int comp = d_comp[p][q];
        v = d_sign[p][q] * Wx[((g * 4 + comp) * 64 + a) * 256 + bcol];
    }
    Wc[idx] = v;
}

// Initialize z[0] (h part = 0, x part = x[t=0]) and c = 0
__global__ __launch_bounds__(256) void init_state(const float* __restrict__ x,
                                                  float* __restrict__ z0,
                                                  float* __restrict__ c) {
    int idx = blockIdx.x * 256 + threadIdx.x;  // over B*KTOT
    if (idx >= B * KTOT) return;
    int b = idx / KTOT, k = idx - b * KTOT;
    if (k < HID) {
        z0[idx] = 0.f;
        c[b * HID + k] = 0.f;
    } else {
        z0[idx] = x[b * FEAT + (k - HID)];     // t = 0
    }
}

// Per-step GEMM: partials[ks][b][n] = sum_{k in chunk ks} z[b][k] * Wc[k][n]
// grid = (NG/64, KSPLIT), block = 256 threads, each thread 4x4 micro-tile.
__global__ __launch_bounds__(256) void gemm_step(const float* __restrict__ z,
                                                 const float* __restrict__ Wc,
                                                 float* __restrict__ part) {
    __shared__ float zs[BK][64];   // [k_local][b]
    __shared__ float wsh[BK][64];  // [k_local][n_local]
    const int n0 = blockIdx.x * 64;
    const int k0 = blockIdx.y * KCHUNK;
    const int tid = threadIdx.x;
    const int tn = (tid & 15) * 4;   // n_local base
    const int tb = (tid >> 4) * 4;   // b base

    float acc[4][4] = {};

    const int kkz = tid & 31, bbz = tid >> 5;     // z loader coords
    const int nlw = tid & 63, kkw = tid >> 6;     // Wc loader coords

    for (int kc = 0; kc < KCHUNK; kc += BK) {
        const int kb = k0 + kc;
        #pragma unroll
        for (int r = 0; r < 8; ++r)
            zs[kkz][bbz + r * 8] = z[(bbz + r * 8) * KTOT + kb + kkz];
        #pragma unroll
        for (int r = 0; r < 8; ++r)
            wsh[kkw + r * 4][nlw] = Wc[(kb + kkw + r * 4) * NG + n0 + nlw];
        __syncthreads();
        #pragma unroll
        for (int kk = 0; kk < BK; ++kk) {
            float4 zv = *(const float4*)&zs[kk][tb];
            float4 wv = *(const float4*)&wsh[kk][tn];
            acc[0][0] += zv.x * wv.x; acc[0][1] += zv.x * wv.y;
            acc[0][2] += zv.x * wv.z; acc[0][3] += zv.x * wv.w;
            acc[1][0] += zv.y * wv.x; acc[1][1] += zv.y * wv.y;
            acc[1][2] += zv.y * wv.z; acc[1][3] += zv.y * wv.w;
            acc[2][0] += zv.z * wv.x; acc[2][1] += zv.z * wv.y;
            acc[2][2] += zv.z * wv.z; acc[2][3] += zv.z * wv.w;
            acc[3][0] += zv.w * wv.x; acc[3][1] += zv.w * wv.y;
            acc[3][2] += zv.w * wv.z; acc[3][3] += zv.w * wv.w;
        }
        __syncthreads();
    }

    float* p = part + blockIdx.y * (B * NG);
    #pragma unroll
    for (int i = 0; i < 4; ++i) {
        float4 v = make_float4(acc[i][0], acc[i][1], acc[i][2], acc[i][3]);
        *(float4*)&p[(tb + i) * NG + n0 + tn] = v;
    }
}

__device__ __forceinline__ float sigmoidf_(float v) { return 1.f / (1.f + expf(-v)); }

// Gate fusion: sum K-split partials + bias, apply LSTM cell, write h to hs and
// znext (plus copy x[t+1] into znext's x slot).
__global__ __launch_bounds__(256) void gate_step(const float* __restrict__ part,
                                                 const float* __restrict__ bx,
                                                 float* __restrict__ c,
                                                 const float* __restrict__ x,
                                                 float* __restrict__ znext,
                                                 float* __restrict__ hs,
                                                 int t) {
    int idx = blockIdx.x * 256 + threadIdx.x;   // over B*HID
    int b = idx >> 10, col = idx & 1023;
    float f = bx[col];
    float i_ = bx[HID + col];
    float o = bx[2 * HID + col];
    float a = bx[3 * HID + col];
    #pragma unroll
    for (int ks = 0; ks < KSPLIT; ++ks) {
        const float* pk = part + ks * (B * NG) + b * NG;
        f  += pk[col];
        i_ += pk[HID + col];
        o  += pk[2 * HID + col];
        a  += pk[3 * HID + col];
    }
    f = sigmoidf_(f);
    i_ = sigmoidf_(i_);
    o = sigmoidf_(o);
    float cn = i_ * tanhf(a) + f * c[idx];
    c[idx] = cn;
    float h = o * tanhf(cn);
    hs[t * (B * HID) + idx] = h;
    znext[b * KTOT + col] = h;
    if (col < FEAT && t + 1 < T)
        znext[b * KTOT + HID + col] = x[((t + 1) * B + b) * FEAT + col];
}

// Output projection: out[m][n] = sum_k hs[m][k]*Wo[k][n] + bo[n], m = t*B+b.
// Each block: 32 rows, cols 0..255 (thread tid -> col tid). Col 256 separate.
__global__ __launch_bounds__(256) void out_gemm(const float* __restrict__ hs,
                                                const float* __restrict__ Wo,
                                                const float* __restrict__ bo,
                                                float* __restrict__ out) {
    __shared__ float hss[32][64];
    const int m0 = blockIdx.x * 32;
    const int tid = threadIdx.x;
    float acc[32];
    float bias = bo[tid];
    #pragma unroll
    for (int m = 0; m < 32; ++m) acc[m] = 0.f;

    const int kkl = tid & 63, mll = tid >> 6;   // loader coords
    for (int k0 = 0; k0 < HID; k0 += 64) {
        #pragma unroll
        for (int r = 0; r < 8; ++r)
            hss[mll + r * 4][kkl] = hs[(m0 + mll + r * 4) * HID + k0 + kkl];
        __syncthreads();
        for (int kk = 0; kk < 64; ++kk) {
            float w = Wo[(k0 + kk) * NCLS + tid];
            #pragma unroll
            for (int m = 0; m < 32; ++m)
                acc[m] += hss[m][kk] * w;
        }
        __syncthreads();
    }
    #pragma unroll
    for (int m = 0; m < 32; ++m)
        out[(m0 + m) * NCLS + tid] = acc[m] + bias;
}

// Last column (n = 256) of the output projection.
__global__ __launch_bounds__(256) void out_col_last(const float* __restrict__ hs,
                                                    const float* __restrict__ Wo,
                                                    const float* __restrict__ bo,
                                                    float* __restrict__ out) {
    int m = blockIdx.x * 256 + threadIdx.x;  // over T*B
    if (m >= T * B) return;
    float acc = bo[NCLS - 1];
    const float* hr = hs + m * HID;
    for (int k = 0; k < HID; k += 4) {
        float4 hv = *(const float4*)&hr[k];
        acc += hv.x * Wo[(k + 0) * NCLS + (NCLS - 1)];
        acc += hv.y * Wo[(k + 1) * NCLS + (NCLS - 1)];
        acc += hv.z * Wo[(k + 2) * NCLS + (NCLS - 1)];
        acc += hv.w * Wo[(k + 3) * NCLS + (NCLS - 1)];
    }
    out[m * NCLS + (NCLS - 1)] = acc;
}

extern "C" void kernel_launch(void* const* d_in, const int* in_sizes, int n_in,
                              void* d_out, int out_size, void* d_ws, size_t ws_size,
                              hipStream_t stream) {
    const float* x  = (const float*)d_in[0];   // [T,B,FEAT]
    const float* Wx = (const float*)d_in[1];   // [4,4,64,256]
    const float* bx = (const float*)d_in[2];   // [4,HID]
    const float* Wh = (const float*)d_in[3];   // [4,4,256,256]
    const float* Wo = (const float*)d_in[4];   // [HID,NCLS]
    const float* bo = (const float*)d_in[5];   // [NCLS]
    float* out = (float*)d_out;

    // Workspace layout (floats)
    float* ws = (float*)d_ws;
    float* Wc    = ws;                               // 1280*4096   = 5,242,880
    float* z0    = Wc + (size_t)KTOT * NG;           // 64*1280     = 81,920
    float* z1    = z0 + (size_t)B * KTOT;            // 64*1280
    float* cbuf  = z1 + (size_t)B * KTOT;            // 64*1024
    float* part  = cbuf + (size_t)B * HID;           // 4*64*4096   = 1,048,576
    float* hsbuf = part + (size_t)KSPLIT * B * NG;   // 256*64*1024 = 16,777,216

    // 1. Build combined Hamilton weight matrix
    build_wc<<<(KTOT * NG + 255) / 256, 256, 0, stream>>>(Wh, Wx, Wc);

    // 2. Init state
    init_state<<<(B * KTOT + 255) / 256, 256, 0, stream>>>(x, z0, cbuf);

    // 3. Recurrence
    float* zbuf[2] = {z0, z1};
    for (int t = 0; t < T; ++t) {
        const float* zc = zbuf[t & 1];
        float* zn = zbuf[(t + 1) & 1];
        gemm_step<<<dim3(NG / 64, KSPLIT), 256, 0, stream>>>(zc, Wc, part);
        gate_step<<<(B * HID) / 256, 256, 0, stream>>>(part, bx, cbuf, x, zn, hsbuf, t);
    }

    // 4. Output projection
    out_gemm<<<(T * B) / 32, 256, 0, stream>>>(hsbuf, Wo, bo, out);
    out_col_last<<<(T * B) / 256, 256, 0, stream>>>(hsbuf, Wo, bo, out);
}